// Round 4
// baseline (132664.270 us; speedup 1.0000x reference)
//
#include <hip/hip_runtime.h>
#include <hip/hip_bf16.h>
#include <hip/hip_cooperative_groups.h>

namespace cg = cooperative_groups;

#define BB 32
#define SS 512
#define DD 512
#define HH 1024
#define KTOT 1536
#define NSL 8          // k-slices per step
#define SLK 192        // k elements per slice

struct Params {
    const float* x;        // [B][S][D]   fp32
    const float* Wi[4];    // [D][H]
    const float* Wh[4];    // [H][H]
    const float* bias[4];  // [H]
    float* out_h;          // [B][S][H] fp32
    float* out_c;          // [B][S][H] fp32
};

__launch_bounds__(256, 4)
__global__ void lstm_valu(Params p) {
    // [slice][row<=255][gate], XOR-swizzled so the 8 slice-lanes of a wave
    // hit distinct bank groups (slice stride 4 KiB is bank-aligned otherwise)
    __shared__ float Wl[NSL * 256 * 4];   // 32 KiB
    __shared__ float c_st[BB];

    const int tid = threadIdx.x;
    const int hc  = blockIdx.x;           // this block's h column

    // ---- stage this column's weights: Wl[ks][rr][g] = Wg[k][hc] ----
    for (int flat = tid; flat < KTOT * 4; flat += 256) {
        const int k = flat >> 2, g = flat & 3;
        const int ks = k / SLK, rr = k - ks * SLK;
        float w = (k < DD) ? p.Wi[g][(size_t)k * HH + hc]
                           : p.Wh[g][(size_t)(k - DD) * HH + hc];
        Wl[((((ks << 8) + rr) << 2) ^ (ks << 2)) + g] = w;
    }
    float bias_v[4];
    #pragma unroll
    for (int g = 0; g < 4; ++g) bias_v[g] = p.bias[g][hc];
    __syncthreads();

    const int b  = tid >> 3;   // batch 0..31
    const int ks = tid & 7;    // k-slice 0..7 (8 lanes reduce together)
    cg::grid_group grid = cg::this_grid();

    for (int t = 0; t < SS; ++t) {
        const int kmax = (t == 0) ? DD : KTOT;   // no h-term at t==0
        float a0 = 0.f, a1 = 0.f, a2 = 0.f, a3 = 0.f;
        const int kbase = ks * SLK;
        const float* hprev = p.out_h + ((size_t)b * SS + (size_t)(t - 1)) * HH;
        const float* xrow  = p.x     + ((size_t)b * SS + (size_t)t) * DD;
        for (int i = 0; i < SLK; ++i) {
            const int k = kbase + i;
            if (k >= kmax) break;
            const float a = (k < DD) ? xrow[k] : hprev[k - DD];
            const float* w = &Wl[(((ks << 8) + i) << 2) ^ (ks << 2)];
            a0 += a * w[0]; a1 += a * w[1]; a2 += a * w[2]; a3 += a * w[3];
        }
        // sum the 8 k-slice partials (lanes b*8+ks live in one wave)
        #pragma unroll
        for (int m = 1; m < 8; m <<= 1) {
            a0 += __shfl_xor(a0, m);
            a1 += __shfl_xor(a1, m);
            a2 += __shfl_xor(a2, m);
            a3 += __shfl_xor(a3, m);
        }
        if (ks == 0) {
            const float ig = 1.f / (1.f + __expf(-(a0 + bias_v[0])));
            const float fg = 1.f / (1.f + __expf(-(a1 + bias_v[1])));
            const float gg = tanhf(a2 + bias_v[2]);
            const float og = 1.f / (1.f + __expf(-(a3 + bias_v[3])));
            const float cp = (t == 0) ? 0.f : c_st[b];
            const float cn = fg * cp + ig * gg;
            const float hn = og * tanhf(cn);
            c_st[b] = cn;
            const size_t o = ((size_t)b * SS + t) * HH + hc;
            p.out_h[o] = hn;   // fp32 store; also the h feedback for t+1
            p.out_c[o] = cn;
        }
        grid.sync();   // h_t visible device-wide before step t+1
    }
}

extern "C" void kernel_launch(void* const* d_in, const int* in_sizes, int n_in,
                              void* d_out, int out_size, void* d_ws, size_t ws_size,
                              hipStream_t stream) {
    (void)in_sizes; (void)n_in; (void)d_ws; (void)ws_size; (void)out_size;
    Params p;
    p.x = (const float*)d_in[0];
    for (int g = 0; g < 4; ++g) {
        p.Wi[g]   = (const float*)d_in[1 + g];
        p.Wh[g]   = (const float*)d_in[5 + g];
        p.bias[g] = (const float*)d_in[9 + g];
    }
    p.out_h = (float*)d_out;
    p.out_c = p.out_h + (size_t)BB * SS * HH;
    void* args[] = { &p };
    hipLaunchCooperativeKernel((void*)lstm_valu, dim3(HH), dim3(256),
                               args, 0, stream);
}

// Round 5
// 18338.493 us; speedup vs baseline: 7.2342x; 7.2342x over previous
//
#include <hip/hip_runtime.h>
#include <hip/hip_bf16.h>
#include <hip/hip_cooperative_groups.h>

namespace cg = cooperative_groups;

typedef __attribute__((ext_vector_type(8))) short bf16x8;
typedef __attribute__((ext_vector_type(4))) float f32x4;

#define BB 32
#define SS 512
#define DD 512
#define HH 1024
#define KTOT (DD + HH)      // 1536
#define NCH 4               // h-columns per block
#define NCOL (NCH * 4)      // 16 gate-columns (4 gates x 4 cols)
#define NBLK 256
#define KPAD (KTOT + 8)     // row stride 3088 B: 16B-aligned, rotates banks by 4/col

struct Params {
    const float* x;        // [B][S][D] fp32
    const float* Wi[4];    // [D][H] fp32
    const float* Wh[4];    // [H][H] fp32
    const float* bias[4];  // [H] fp32
    float* out_h;          // [B][S][H] fp32
    float* out_c;          // [B][S][H] fp32
    __hip_bfloat16* hws;   // [2][B][H] bf16 h ping-pong (in d_ws)
};

static __device__ __forceinline__ short f2bf(float f) {
    __hip_bfloat16 h = __float2bfloat16(f);
    return *reinterpret_cast<short*>(&h);
}

__launch_bounds__(256, 1)
__global__ void lstm_mfma(Params p) {
    __shared__ short Wl[NCOL][KPAD];      // bf16 weights, 49.4 KB
    __shared__ float accl[2][BB][NCOL];   // [k-half][batch][col]
    __shared__ float c_st[BB][NCH];       // fp32 cell state
    __shared__ float bias_l[NCOL];

    const int tid = threadIdx.x;
    const int hc0 = blockIdx.x * NCH;

    // ---- stage weights to LDS once: Wl[g*4+j][k] = Wg[k][hc0+j], coalesced f32x4 rows ----
    for (int idx = tid; idx < KTOT * 4; idx += 256) {
        const int r = idx >> 2, g = idx & 3;
        f32x4 w = (r < DD)
            ? *(const f32x4*)&p.Wi[g][(size_t)r * HH + hc0]
            : *(const f32x4*)&p.Wh[g][(size_t)(r - DD) * HH + hc0];
        #pragma unroll
        for (int j = 0; j < 4; ++j) Wl[g * 4 + j][r] = f2bf(w[j]);
    }
    if (tid < NCOL) bias_l[tid] = p.bias[tid >> 2][hc0 + (tid & 3)];
    __syncthreads();

    const int wave = tid >> 6;
    const int lane = tid & 63;
    const int mi  = wave & 1;               // batch half
    const int kh  = wave >> 1;              // K half
    const int row = mi * 16 + (lane & 15);  // batch index for A
    const int col = lane & 15;              // gate-col for B
    const int kg  = lane >> 4;              // k-subgroup 0..3

    const int nx = (kh == 0) ? 16 : 0;      // x-chunks this wave (k 0..511)
    const int hb = (kh == 0) ? 0 : 256;     // h-part base
    const int nh_full = (kh == 0) ? 8 : 24; // h-chunks when t>0

    cg::grid_group grid = cg::this_grid();

    const float* xbase = p.x + (size_t)row * SS * DD;

    for (int t = 0; t < SS; ++t) {
        const float* xrow = xbase + (size_t)t * DD;
        const __hip_bfloat16* hrow =
            p.hws + (size_t)((t - 1) & 1) * (BB * HH) + (size_t)row * HH;
        const int nh = (t == 0) ? 0 : nh_full;

        f32x4 acc = {0.f, 0.f, 0.f, 0.f};
        #pragma unroll 4
        for (int cx = 0; cx < nx; ++cx) {           // x-part: fp32 -> bf16
            const int k0 = cx * 32 + kg * 8;
            f32x4 a0 = *(const f32x4*)(xrow + k0);
            f32x4 a1 = *(const f32x4*)(xrow + k0 + 4);
            bf16x8 a;
            a[0] = f2bf(a0[0]); a[1] = f2bf(a0[1]);
            a[2] = f2bf(a0[2]); a[3] = f2bf(a0[3]);
            a[4] = f2bf(a1[0]); a[5] = f2bf(a1[1]);
            a[6] = f2bf(a1[2]); a[7] = f2bf(a1[3]);
            bf16x8 b = *(const bf16x8*)&Wl[col][k0];
            acc = __builtin_amdgcn_mfma_f32_16x16x32_bf16(a, b, acc, 0, 0, 0);
        }
        #pragma unroll 4
        for (int ch = 0; ch < nh; ++ch) {           // h-part: bf16 direct
            const int hk = hb + ch * 32 + kg * 8;
            bf16x8 a = *(const bf16x8*)(hrow + hk);
            bf16x8 b = *(const bf16x8*)&Wl[col][DD + hk];
            acc = __builtin_amdgcn_mfma_f32_16x16x32_bf16(a, b, acc, 0, 0, 0);
        }
        #pragma unroll
        for (int i = 0; i < 4; ++i)
            accl[kh][mi * 16 + kg * 4 + i][col] = acc[i];
        __syncthreads();

        if (tid < BB * NCH) {              // 128 threads: one (batch, h-col) each
            const int b = tid >> 2, j = tid & 3;
            float pre[4];
            #pragma unroll
            for (int g = 0; g < 4; ++g) {
                const int c = g * NCH + j;
                pre[g] = accl[0][b][c] + accl[1][b][c] + bias_l[c];
            }
            const float ig = 1.f / (1.f + __expf(-pre[0]));
            const float fg = 1.f / (1.f + __expf(-pre[1]));
            const float gg = tanhf(pre[2]);
            const float og = 1.f / (1.f + __expf(-pre[3]));
            const float cp = (t == 0) ? 0.f : c_st[b][j];
            const float cn = fg * cp + ig * gg;
            const float hn = og * tanhf(cn);
            c_st[b][j] = cn;
            const size_t o = ((size_t)b * SS + t) * HH + hc0 + j;
            p.out_h[o] = hn;
            p.out_c[o] = cn;
            p.hws[(size_t)(t & 1) * (BB * HH) + (size_t)b * HH + hc0 + j] =
                __float2bfloat16(hn);
        }
        grid.sync();   // h_t visible device-wide before step t+1
    }
}

extern "C" void kernel_launch(void* const* d_in, const int* in_sizes, int n_in,
                              void* d_out, int out_size, void* d_ws, size_t ws_size,
                              hipStream_t stream) {
    (void)in_sizes; (void)n_in; (void)ws_size; (void)out_size;
    Params p;
    p.x = (const float*)d_in[0];
    for (int g = 0; g < 4; ++g) {
        p.Wi[g]   = (const float*)d_in[1 + g];
        p.Wh[g]   = (const float*)d_in[5 + g];
        p.bias[g] = (const float*)d_in[9 + g];
    }
    p.out_h = (float*)d_out;
    p.out_c = p.out_h + (size_t)BB * SS * HH;
    p.hws   = (__hip_bfloat16*)d_ws;
    void* args[] = { &p };
    hipLaunchCooperativeKernel((void*)lstm_mfma, dim3(NBLK), dim3(256),
                               args, 0, stream);
}

// Round 6
// 8448.932 us; speedup vs baseline: 15.7019x; 2.1705x over previous
//
#include <hip/hip_runtime.h>
#include <hip/hip_bf16.h>

typedef __attribute__((ext_vector_type(8))) short bf16x8;
typedef __attribute__((ext_vector_type(4))) float f32x4;

#define BB 32
#define SS 512
#define DD 512
#define HH 1024
#define KTOT (DD + HH)      // 1536
#define NCH 4               // h-columns per block
#define NCOL 16             // 4 gates x 4 cols
#define NBLK 256
#define KPAD (KTOT + 8)
#define HW2 (HH / 2)        // h row in packed u32 (2 bf16 each)

// Cross-block state: zero-initialized device globals, self-reset each run.
__device__ unsigned int g_bar[SS];                // per-step arrival counters
__device__ unsigned int g_done;                   // end-of-run reset rendezvous
__device__ unsigned int g_hws[2 * BB * HW2];      // bf16-pair h ping-pong

struct Params {
    const float* x;        // [B][S][D] fp32
    const float* Wi[4];    // [D][H]
    const float* Wh[4];    // [H][H]
    const float* bias[4];  // [H]
    float* out_h;          // [B][S][H] fp32
    float* out_c;          // [B][S][H] fp32
};

static __device__ __forceinline__ short f2bf(float f) {
    __hip_bfloat16 h = __float2bfloat16(f);
    return *reinterpret_cast<short*>(&h);
}

__launch_bounds__(256, 1)
__global__ void lstm_mfma(Params p) {
    __shared__ short Wl[NCOL][KPAD];      // bf16 weights, 49.4 KB
    __shared__ float accl[2][BB][NCOL];   // [k-half][batch][col]
    __shared__ float c_st[BB][NCH];       // fp32 cell state
    __shared__ float bias_l[NCOL];

    const int tid = threadIdx.x;
    const int hc0 = blockIdx.x * NCH;

    // ---- stage weights to LDS once (coalesced f32x4 rows, cached loads) ----
    for (int idx = tid; idx < KTOT * 4; idx += 256) {
        const int r = idx >> 2, g = idx & 3;
        f32x4 w = (r < DD)
            ? *(const f32x4*)&p.Wi[g][(size_t)r * HH + hc0]
            : *(const f32x4*)&p.Wh[g][(size_t)(r - DD) * HH + hc0];
        #pragma unroll
        for (int j = 0; j < 4; ++j) Wl[g * 4 + j][r] = f2bf(w[j]);
    }
    if (tid < NCOL) bias_l[tid] = p.bias[tid >> 2][hc0 + (tid & 3)];
    __syncthreads();

    const int wave = tid >> 6;
    const int lane = tid & 63;
    const int mi  = wave & 1;               // batch half
    const int kh  = wave >> 1;              // K half
    const int row = mi * 16 + (lane & 15);  // batch index for A
    const int col = lane & 15;              // gate-col for B
    const int kg  = lane >> 4;              // k-subgroup 0..3

    // x-part for one step (8 chunks/wave: k = kh*256 + cx*32 + kg*8)
    auto xpart = [&](int t, f32x4 a_cc) -> f32x4 {
        const float* xrow = p.x + ((size_t)row * SS + t) * DD;
        #pragma unroll 4
        for (int cx = 0; cx < 8; ++cx) {
            const int k0 = kh * 256 + cx * 32 + kg * 8;
            f32x4 a0 = *(const f32x4*)(xrow + k0);
            f32x4 a1 = *(const f32x4*)(xrow + k0 + 4);
            bf16x8 a;
            a[0] = f2bf(a0[0]); a[1] = f2bf(a0[1]);
            a[2] = f2bf(a0[2]); a[3] = f2bf(a0[3]);
            a[4] = f2bf(a1[0]); a[5] = f2bf(a1[1]);
            a[6] = f2bf(a1[2]); a[7] = f2bf(a1[3]);
            bf16x8 b = *(const bf16x8*)&Wl[col][k0];
            a_cc = __builtin_amdgcn_mfma_f32_16x16x32_bf16(a, b, a_cc, 0, 0, 0);
        }
        return a_cc;
    };

    f32x4 acc = {0.f, 0.f, 0.f, 0.f};
    acc = xpart(0, acc);                   // prologue: x-part of t=0

    for (int t = 0; t < SS; ++t) {
        if (t > 0) {
            // ---- wait: h_{t-1} published device-wide ----
            unsigned it = 0;
            while (__hip_atomic_load(&g_bar[t - 1], __ATOMIC_RELAXED,
                                     __HIP_MEMORY_SCOPE_AGENT) < NBLK) {
                __builtin_amdgcn_s_sleep(2);
                if (++it > (1u << 20)) break;   // bailout: fail loud, not hang
            }
            asm volatile("" ::: "memory");

            // ---- h-part: 16 chunks/wave, coherent u64 loads from IF ----
            unsigned long long* hrow = (unsigned long long*)
                (g_hws + ((t - 1) & 1) * (BB * HW2) + row * HW2);
            #pragma unroll 4
            for (int ch = 0; ch < 16; ++ch) {
                const int hk = kh * 512 + ch * 32 + kg * 8;
                unsigned long long q0 = __hip_atomic_load(hrow + (hk >> 2),
                    __ATOMIC_RELAXED, __HIP_MEMORY_SCOPE_AGENT);
                unsigned long long q1 = __hip_atomic_load(hrow + (hk >> 2) + 1,
                    __ATOMIC_RELAXED, __HIP_MEMORY_SCOPE_AGENT);
                bf16x8 a;
                a[0] = (short)(q0);       a[1] = (short)(q0 >> 16);
                a[2] = (short)(q0 >> 32); a[3] = (short)(q0 >> 48);
                a[4] = (short)(q1);       a[5] = (short)(q1 >> 16);
                a[6] = (short)(q1 >> 32); a[7] = (short)(q1 >> 48);
                bf16x8 b = *(const bf16x8*)&Wl[col][DD + hk];
                acc = __builtin_amdgcn_mfma_f32_16x16x32_bf16(a, b, acc, 0, 0, 0);
            }
        }
        #pragma unroll
        for (int i = 0; i < 4; ++i)
            accl[kh][mi * 16 + kg * 4 + i][col] = acc[i];
        __syncthreads();

        if (tid < 64) {                    // gating: one (batch, col-pair) each
            const int b = tid >> 1, jp = (tid & 1) * 2;
            float hn2[2], cn2[2];
            #pragma unroll
            for (int u = 0; u < 2; ++u) {
                const int j = jp + u;
                float pre[4];
                #pragma unroll
                for (int g = 0; g < 4; ++g) {
                    const int c = g * NCH + j;
                    pre[g] = accl[0][b][c] + accl[1][b][c] + bias_l[c];
                }
                const float ig = 1.f / (1.f + __expf(-pre[0]));
                const float fg = 1.f / (1.f + __expf(-pre[1]));
                const float gg = tanhf(pre[2]);
                const float og = 1.f / (1.f + __expf(-pre[3]));
                const float cp = (t == 0) ? 0.f : c_st[b][j];
                const float cn = fg * cp + ig * gg;
                const float hn = og * tanhf(cn);
                c_st[b][j] = cn;
                hn2[u] = hn; cn2[u] = cn;
            }
            const size_t o = ((size_t)b * SS + t) * HH + hc0 + jp;
            *(float2*)&p.out_h[o] = make_float2(hn2[0], hn2[1]);
            *(float2*)&p.out_c[o] = make_float2(cn2[0], cn2[1]);
            unsigned pack = (unsigned)(unsigned short)f2bf(hn2[0])
                          | ((unsigned)(unsigned short)f2bf(hn2[1]) << 16);
            __hip_atomic_store(
                &g_hws[(t & 1) * (BB * HW2) + b * HW2 + ((hc0 + jp) >> 1)],
                pack, __ATOMIC_RELAXED, __HIP_MEMORY_SCOPE_AGENT);
            // ack: h-stores reached the coherence point before we arrive
            asm volatile("s_waitcnt vmcnt(0)" ::: "memory");
        }
        if (t == SS - 1) break;
        if (tid == 0)
            __hip_atomic_fetch_add(&g_bar[t], 1u, __ATOMIC_RELAXED,
                                   __HIP_MEMORY_SCOPE_AGENT);
        // ---- hide barrier propagation: x-part of t+1 (h-independent) ----
        acc = (f32x4){0.f, 0.f, 0.f, 0.f};
        acc = xpart(t + 1, acc);
    }

    // ---- end-of-run: last block resets barrier state for the next replay ----
    if (tid == 0) {
        unsigned v = __hip_atomic_fetch_add(&g_done, 1u, __ATOMIC_RELAXED,
                                            __HIP_MEMORY_SCOPE_AGENT) + 1;
        if (v == NBLK) {
            for (int i = 0; i < SS; ++i)
                __hip_atomic_store(&g_bar[i], 0u, __ATOMIC_RELAXED,
                                   __HIP_MEMORY_SCOPE_AGENT);
            __hip_atomic_store(&g_done, 0u, __ATOMIC_RELAXED,
                               __HIP_MEMORY_SCOPE_AGENT);
        }
    }
}

extern "C" void kernel_launch(void* const* d_in, const int* in_sizes, int n_in,
                              void* d_out, int out_size, void* d_ws, size_t ws_size,
                              hipStream_t stream) {
    (void)in_sizes; (void)n_in; (void)d_ws; (void)ws_size; (void)out_size;
    Params p;
    p.x = (const float*)d_in[0];
    for (int g = 0; g < 4; ++g) {
        p.Wi[g]   = (const float*)d_in[1 + g];
        p.Wh[g]   = (const float*)d_in[5 + g];
        p.bias[g] = (const float*)d_in[9 + g];
    }
    p.out_h = (float*)d_out;
    p.out_c = p.out_h + (size_t)BB * SS * HH;
    lstm_mfma<<<dim3(NBLK), dim3(256), 0, stream>>>(p);
}

// Round 7
// 3701.019 us; speedup vs baseline: 35.8453x; 2.2829x over previous
//
#include <hip/hip_runtime.h>
#include <hip/hip_bf16.h>

typedef __attribute__((ext_vector_type(8))) short bf16x8;
typedef __attribute__((ext_vector_type(4))) float f32x4;

#define BB 32
#define SS 512
#define DD 512
#define HH 1024
#define KTOT (DD + HH)      // 1536
#define NCH 4               // h-columns per block
#define NCOL 16             // 4 gates x 4 cols
#define NBLK 256
#define KPAD (KTOT + 8)
#define HW2 (HH / 2)        // h row in packed u32 (2 bf16 each)

// Cross-block state: zero-initialized device globals, self-reset each run.
__device__ unsigned int g_flag[NBLK * 16];        // per-block step flag, 64B-padded
__device__ unsigned int g_done;                   // end-of-run reset rendezvous
__device__ unsigned int g_hws[2 * BB * HW2];      // bf16-pair h ping-pong

struct Params {
    const float* x;        // [B][S][D] fp32
    const float* Wi[4];    // [D][H]
    const float* Wh[4];    // [H][H]
    const float* bias[4];  // [H]
    float* out_h;          // [B][S][H] fp32
    float* out_c;          // [B][S][H] fp32
};

static __device__ __forceinline__ short f2bf(float f) {
    __hip_bfloat16 h = __float2bfloat16(f);
    return *reinterpret_cast<short*>(&h);
}

static __device__ __forceinline__ unsigned ldflag(int i) {
    return __hip_atomic_load(&g_flag[i << 4], __ATOMIC_RELAXED,
                             __HIP_MEMORY_SCOPE_AGENT);
}

__launch_bounds__(256, 1)
__global__ void lstm_mfma(Params p) {
    __shared__ short Wl[NCOL][KPAD];      // bf16 weights, 49.4 KB
    __shared__ float accl[2][BB][NCOL];   // [k-half][batch][col]
    __shared__ float c_st[BB][NCH];       // fp32 cell state
    __shared__ float bias_l[NCOL];
    __shared__ unsigned rel;              // LDS relay: last step whose h is ready

    const int tid = threadIdx.x;
    const int hc0 = blockIdx.x * NCH;

    if (tid == 0)
        __hip_atomic_store(&rel, 0u, __ATOMIC_RELAXED, __HIP_MEMORY_SCOPE_WORKGROUP);

    // ---- stage weights to LDS once (coalesced f32x4 rows, cached loads) ----
    for (int idx = tid; idx < KTOT * 4; idx += 256) {
        const int r = idx >> 2, g = idx & 3;
        f32x4 w = (r < DD)
            ? *(const f32x4*)&p.Wi[g][(size_t)r * HH + hc0]
            : *(const f32x4*)&p.Wh[g][(size_t)(r - DD) * HH + hc0];
        #pragma unroll
        for (int j = 0; j < 4; ++j) Wl[g * 4 + j][r] = f2bf(w[j]);
    }
    if (tid < NCOL) bias_l[tid] = p.bias[tid >> 2][hc0 + (tid & 3)];
    __syncthreads();

    const int wave = tid >> 6;
    const int lane = tid & 63;
    const int mi  = wave & 1;               // batch half
    const int kh  = wave >> 1;              // K half
    const int row = mi * 16 + (lane & 15);  // batch index for A
    const int col = lane & 15;              // gate-col for B
    const int kg  = lane >> 4;              // k-subgroup 0..3
    const int f0  = lane * 4;               // this lane's 4 flags to poll

    // x-part for one step (8 chunks/wave: k = kh*256 + cx*32 + kg*8)
    auto xpart = [&](int t, f32x4 a_cc) -> f32x4 {
        const float* xrow = p.x + ((size_t)row * SS + t) * DD;
        #pragma unroll 4
        for (int cx = 0; cx < 8; ++cx) {
            const int k0 = kh * 256 + cx * 32 + kg * 8;
            f32x4 a0 = *(const f32x4*)(xrow + k0);
            f32x4 a1 = *(const f32x4*)(xrow + k0 + 4);
            bf16x8 a;
            a[0] = f2bf(a0[0]); a[1] = f2bf(a0[1]);
            a[2] = f2bf(a0[2]); a[3] = f2bf(a0[3]);
            a[4] = f2bf(a1[0]); a[5] = f2bf(a1[1]);
            a[6] = f2bf(a1[2]); a[7] = f2bf(a1[3]);
            bf16x8 b = *(const bf16x8*)&Wl[col][k0];
            a_cc = __builtin_amdgcn_mfma_f32_16x16x32_bf16(a, b, a_cc, 0, 0, 0);
        }
        return a_cc;
    };

    f32x4 acc = {0.f, 0.f, 0.f, 0.f};
    acc = xpart(0, acc);                   // prologue: x-part of t=0

    for (int t = 0; t < SS; ++t) {
        if (t > 0) {
            // ---- wait: all blocks finished step t-1 (flags >= t) ----
            if (wave == 0) {
                unsigned it = 0;
                for (;;) {
                    unsigned v0 = ldflag(f0 + 0), v1 = ldflag(f0 + 1);
                    unsigned v2 = ldflag(f0 + 2), v3 = ldflag(f0 + 3);
                    unsigned mn = min(min(v0, v1), min(v2, v3));
                    if (__all(mn >= (unsigned)t)) break;
                    __builtin_amdgcn_s_sleep(2);
                    if (++it > (1u << 20)) break;   // fail loud, not hang
                }
                if (lane == 0)
                    __hip_atomic_store(&rel, (unsigned)t, __ATOMIC_RELAXED,
                                       __HIP_MEMORY_SCOPE_WORKGROUP);
            } else {
                unsigned it = 0;
                while (__hip_atomic_load(&rel, __ATOMIC_RELAXED,
                                         __HIP_MEMORY_SCOPE_WORKGROUP) < (unsigned)t) {
                    __builtin_amdgcn_s_sleep(1);
                    if (++it > (1u << 22)) break;
                }
            }
            asm volatile("" ::: "memory");

            // ---- h-part: 16 chunks/wave, coherent u64 loads from IF ----
            unsigned long long* hrow = (unsigned long long*)
                (g_hws + ((t - 1) & 1) * (BB * HW2) + row * HW2);
            #pragma unroll 4
            for (int ch = 0; ch < 16; ++ch) {
                const int hk = kh * 512 + ch * 32 + kg * 8;
                unsigned long long q0 = __hip_atomic_load(hrow + (hk >> 2),
                    __ATOMIC_RELAXED, __HIP_MEMORY_SCOPE_AGENT);
                unsigned long long q1 = __hip_atomic_load(hrow + (hk >> 2) + 1,
                    __ATOMIC_RELAXED, __HIP_MEMORY_SCOPE_AGENT);
                bf16x8 a;
                a[0] = (short)(q0);       a[1] = (short)(q0 >> 16);
                a[2] = (short)(q0 >> 32); a[3] = (short)(q0 >> 48);
                a[4] = (short)(q1);       a[5] = (short)(q1 >> 16);
                a[6] = (short)(q1 >> 32); a[7] = (short)(q1 >> 48);
                bf16x8 b = *(const bf16x8*)&Wl[col][DD + hk];
                acc = __builtin_amdgcn_mfma_f32_16x16x32_bf16(a, b, acc, 0, 0, 0);
            }
        }
        #pragma unroll
        for (int i = 0; i < 4; ++i)
            accl[kh][mi * 16 + kg * 4 + i][col] = acc[i];
        __syncthreads();

        if (tid < 64) {                    // gating: one (batch, col-pair) each
            const int b = tid >> 1, jp = (tid & 1) * 2;
            float hn2[2], cn2[2];
            #pragma unroll
            for (int u = 0; u < 2; ++u) {
                const int j = jp + u;
                float pre[4];
                #pragma unroll
                for (int g = 0; g < 4; ++g) {
                    const int c = g * NCH + j;
                    pre[g] = accl[0][b][c] + accl[1][b][c] + bias_l[c];
                }
                const float ig = 1.f / (1.f + __expf(-pre[0]));
                const float fg = 1.f / (1.f + __expf(-pre[1]));
                const float gg = tanhf(pre[2]);
                const float og = 1.f / (1.f + __expf(-pre[3]));
                const float cp = (t == 0) ? 0.f : c_st[b][j];
                const float cn = fg * cp + ig * gg;
                const float hn = og * tanhf(cn);
                c_st[b][j] = cn;
                hn2[u] = hn; cn2[u] = cn;
            }
            const size_t o = ((size_t)b * SS + t) * HH + hc0 + jp;
            *(float2*)&p.out_h[o] = make_float2(hn2[0], hn2[1]);
            *(float2*)&p.out_c[o] = make_float2(cn2[0], cn2[1]);
            unsigned pack = (unsigned)(unsigned short)f2bf(hn2[0])
                          | ((unsigned)(unsigned short)f2bf(hn2[1]) << 16);
            __hip_atomic_store(
                &g_hws[(t & 1) * (BB * HW2) + b * HW2 + ((hc0 + jp) >> 1)],
                pack, __ATOMIC_RELAXED, __HIP_MEMORY_SCOPE_AGENT);
            // wave-level ack: all 64 lanes' h-stores reached coherence point
            asm volatile("s_waitcnt vmcnt(0)" ::: "memory");
            if (tid == 0 && t < SS - 1)
                __hip_atomic_store(&g_flag[blockIdx.x << 4], (unsigned)(t + 1),
                                   __ATOMIC_RELAXED, __HIP_MEMORY_SCOPE_AGENT);
        }
        if (t == SS - 1) break;
        // ---- hide barrier propagation: x-part of t+1 (h-independent) ----
        acc = (f32x4){0.f, 0.f, 0.f, 0.f};
        acc = xpart(t + 1, acc);
    }

    // ---- end-of-run: last block resets flags for the next graph replay ----
    __syncthreads();
    if (tid == 0) {
        unsigned v = __hip_atomic_fetch_add(&g_done, 1u, __ATOMIC_RELAXED,
                                            __HIP_MEMORY_SCOPE_AGENT) + 1;
        if (v == NBLK) {
            for (int i = 0; i < NBLK; ++i)
                __hip_atomic_store(&g_flag[i << 4], 0u, __ATOMIC_RELAXED,
                                   __HIP_MEMORY_SCOPE_AGENT);
            __hip_atomic_store(&g_done, 0u, __ATOMIC_RELAXED,
                               __HIP_MEMORY_SCOPE_AGENT);
        }
    }
}

extern "C" void kernel_launch(void* const* d_in, const int* in_sizes, int n_in,
                              void* d_out, int out_size, void* d_ws, size_t ws_size,
                              hipStream_t stream) {
    (void)in_sizes; (void)n_in; (void)d_ws; (void)ws_size; (void)out_size;
    Params p;
    p.x = (const float*)d_in[0];
    for (int g = 0; g < 4; ++g) {
        p.Wi[g]   = (const float*)d_in[1 + g];
        p.Wh[g]   = (const float*)d_in[5 + g];
        p.bias[g] = (const float*)d_in[9 + g];
    }
    p.out_h = (float*)d_out;
    p.out_c = p.out_h + (size_t)BB * SS * HH;
    lstm_mfma<<<dim3(NBLK), dim3(256), 0, stream>>>(p);
}

// Round 8
// 2641.898 us; speedup vs baseline: 50.2155x; 1.4009x over previous
//
#include <hip/hip_runtime.h>
#include <hip/hip_bf16.h>

typedef __attribute__((ext_vector_type(8))) short bf16x8;
typedef __attribute__((ext_vector_type(4))) float f32x4;

#define BB 32
#define SS 512
#define DD 512
#define HH 1024
#define KTOT (DD + HH)      // 1536
#define NCH 8               // h-columns per block
#define NCOL 32             // 4 gates x 8 cols
#define NBLK 256
#define NGRP 2              // independent batch groups
#define GBLK 128            // blocks per group
#define NB2 16              // batches per group
#define KPAD (KTOT + 8)
#define HW2 (HH / 2)        // h row in packed u32 (2 bf16 each)

// Cross-block state: zero-initialized device globals, self-reset each run.
__device__ unsigned int g_flag[NBLK * 16];        // per-block step flag, 64B-padded
__device__ unsigned int g_done;                   // end-of-run reset rendezvous
__device__ unsigned int g_hws[2 * BB * HW2];      // bf16-pair h ping-pong

struct Params {
    const float* x;        // [B][S][D] fp32
    const float* Wi[4];    // [D][H]
    const float* Wh[4];    // [H][H]
    const float* bias[4];  // [H]
    float* out_h;          // [B][S][H] fp32
    float* out_c;          // [B][S][H] fp32
};

static __device__ __forceinline__ short f2bf(float f) {
    __hip_bfloat16 h = __float2bfloat16(f);
    return *reinterpret_cast<short*>(&h);
}

static __device__ __forceinline__ unsigned ldflag(int slot) {
    return __hip_atomic_load(&g_flag[slot << 4], __ATOMIC_RELAXED,
                             __HIP_MEMORY_SCOPE_AGENT);
}

__launch_bounds__(256, 1)
__global__ void lstm_mfma(Params p) {
    __shared__ short Wl[NCOL][KPAD];      // bf16 weights, 98.8 KB
    __shared__ float accl[2][NB2][NCOL];  // [k-half][batch][gate-col]
    __shared__ float c_st[NB2][NCH];      // fp32 cell state
    __shared__ float bias_l[NCOL];
    __shared__ unsigned rel;              // LDS relay: last step whose h is ready

    const int tid = threadIdx.x;
    const int blk = blockIdx.x;
    const int gid = blk & 1;              // batch group (even/odd -> disjoint XCD sets)
    const int lid = blk >> 1;             // 0..127 within group
    const int bb0 = gid * NB2;            // first batch row
    const int hc0 = lid * NCH;            // first h column

    if (tid == 0)
        __hip_atomic_store(&rel, 0u, __ATOMIC_RELAXED, __HIP_MEMORY_SCOPE_WORKGROUP);

    // ---- stage weights to LDS once: Wl[g*8+j][k] = Wg[k][hc0+j] ----
    for (int idx = tid; idx < KTOT * 8; idx += 256) {
        const int r = idx >> 3, q = idx & 7;
        const int g = q >> 1, half = (q & 1) * 4;
        f32x4 w = (r < DD)
            ? *(const f32x4*)&p.Wi[g][(size_t)r * HH + hc0 + half]
            : *(const f32x4*)&p.Wh[g][(size_t)(r - DD) * HH + hc0 + half];
        #pragma unroll
        for (int jj = 0; jj < 4; ++jj) Wl[g * 8 + half + jj][r] = f2bf(w[jj]);
    }
    if (tid < NCOL) bias_l[tid] = p.bias[tid >> 3][hc0 + (tid & 7)];
    __syncthreads();

    const int wave = tid >> 6;
    const int lane = tid & 63;
    const int ct  = wave & 1;               // col-tile (16 gate-cols each)
    const int kh  = wave >> 1;              // K half
    const int arow = bb0 + (lane & 15);     // global batch row for A
    const int gc  = ct * 16 + (lane & 15);  // gate-col for B
    const int kg  = lane >> 4;              // k-subgroup 0..3
    const int khb = kh * 512;               // h-part k base (within h)
    const int kgb = kg * 8;

    // x-part for one step (8 chunks/wave: k = kh*256 + cx*32 + kg*8)
    auto xpart = [&](int t, f32x4 a_cc) -> f32x4 {
        const float* xrow = p.x + ((size_t)arow * SS + t) * DD;
        #pragma unroll 4
        for (int cx = 0; cx < 8; ++cx) {
            const int k0 = kh * 256 + cx * 32 + kgb;
            f32x4 a0 = *(const f32x4*)(xrow + k0);
            f32x4 a1 = *(const f32x4*)(xrow + k0 + 4);
            bf16x8 a;
            a[0] = f2bf(a0[0]); a[1] = f2bf(a0[1]);
            a[2] = f2bf(a0[2]); a[3] = f2bf(a0[3]);
            a[4] = f2bf(a1[0]); a[5] = f2bf(a1[1]);
            a[6] = f2bf(a1[2]); a[7] = f2bf(a1[3]);
            bf16x8 b = *(const bf16x8*)&Wl[gc][k0];
            a_cc = __builtin_amdgcn_mfma_f32_16x16x32_bf16(a, b, a_cc, 0, 0, 0);
        }
        return a_cc;
    };

    f32x4 acc = {0.f, 0.f, 0.f, 0.f};
    acc = xpart(0, acc);                   // prologue: x-part of t=0

    for (int t = 0; t < SS; ++t) {
        if (t > 0) {
            // ---- wait: all 128 group blocks finished step t-1 ----
            if (wave == 0) {
                const int s0 = gid * GBLK + lane * 2;
                unsigned it = 0;
                for (;;) {
                    unsigned v0 = ldflag(s0), v1 = ldflag(s0 + 1);
                    if (__all(min(v0, v1) >= (unsigned)t)) break;
                    __builtin_amdgcn_s_sleep(2);
                    if (++it > (1u << 20)) break;   // fail loud, not hang
                }
                if (lane == 0)
                    __hip_atomic_store(&rel, (unsigned)t, __ATOMIC_RELAXED,
                                       __HIP_MEMORY_SCOPE_WORKGROUP);
            } else {
                unsigned it = 0;
                while (__hip_atomic_load(&rel, __ATOMIC_RELAXED,
                                         __HIP_MEMORY_SCOPE_WORKGROUP) < (unsigned)t) {
                    __builtin_amdgcn_s_sleep(1);
                    if (++it > (1u << 22)) break;
                }
            }
            asm volatile("" ::: "memory");

            // ---- h-part: 16 batched coherent 16B loads, then 16 MFMAs ----
            {
                const unsigned* hb = g_hws + ((t - 1) & 1) * (BB * HW2)
                                   + (size_t)arow * HW2 + kh * 256 + kg * 4;
                bf16x8 h00,h01,h02,h03,h04,h05,h06,h07,
                       h08,h09,h10,h11,h12,h13,h14,h15;
#define LDH(dst, OFF) asm volatile("global_load_dwordx4 %0, %1, off offset:" OFF " sc0 sc1" \
                                   : "=v"(dst) : "v"(hb))
                LDH(h00, "0");   LDH(h01, "64");  LDH(h02, "128"); LDH(h03, "192");
                LDH(h04, "256"); LDH(h05, "320"); LDH(h06, "384"); LDH(h07, "448");
                LDH(h08, "512"); LDH(h09, "576"); LDH(h10, "640"); LDH(h11, "704");
                LDH(h12, "768"); LDH(h13, "832"); LDH(h14, "896"); LDH(h15, "960");
#undef LDH
                asm volatile("s_waitcnt vmcnt(0)" ::: "memory");
                __builtin_amdgcn_sched_barrier(0);
#define FMH(v, CH) acc = __builtin_amdgcn_mfma_f32_16x16x32_bf16( \
                        (v), *(const bf16x8*)&Wl[gc][DD + khb + (CH) * 32 + kgb], acc, 0, 0, 0)
                FMH(h00, 0);  FMH(h01, 1);  FMH(h02, 2);  FMH(h03, 3);
                FMH(h04, 4);  FMH(h05, 5);  FMH(h06, 6);  FMH(h07, 7);
                FMH(h08, 8);  FMH(h09, 9);  FMH(h10, 10); FMH(h11, 11);
                FMH(h12, 12); FMH(h13, 13); FMH(h14, 14); FMH(h15, 15);
#undef FMH
            }
        }
        #pragma unroll
        for (int i = 0; i < 4; ++i)
            accl[kh][(lane >> 4) * 4 + i][gc] = acc[i];
        __syncthreads();

        if (tid < 64) {                    // gating: lane -> (batch, col-pair)
            const int b = lane >> 2, jp = (lane & 3) * 2;
            float hn2[2], cn2[2];
            #pragma unroll
            for (int u = 0; u < 2; ++u) {
                const int j = jp + u;
                float pre[4];
                #pragma unroll
                for (int g = 0; g < 4; ++g) {
                    const int c = g * 8 + j;
                    pre[g] = accl[0][b][c] + accl[1][b][c] + bias_l[c];
                }
                const float ig = 1.f / (1.f + __expf(-pre[0]));
                const float fg = 1.f / (1.f + __expf(-pre[1]));
                const float gg = tanhf(pre[2]);
                const float og = 1.f / (1.f + __expf(-pre[3]));
                const float cp = (t == 0) ? 0.f : c_st[b][j];
                const float cn = fg * cp + ig * gg;
                const float hn = og * tanhf(cn);
                c_st[b][j] = cn;
                hn2[u] = hn; cn2[u] = cn;
            }
            unsigned pack = (unsigned)(unsigned short)f2bf(hn2[0])
                          | ((unsigned)(unsigned short)f2bf(hn2[1]) << 16);
            __hip_atomic_store(
                &g_hws[(t & 1) * (BB * HW2) + (bb0 + b) * HW2 + ((hc0 + jp) >> 1)],
                pack, __ATOMIC_RELAXED, __HIP_MEMORY_SCOPE_AGENT);
            // wave-level ack: all lanes' h-stores reached the coherence point
            asm volatile("s_waitcnt vmcnt(0)" ::: "memory");
            if (lane == 0 && t < SS - 1)
                __hip_atomic_store(&g_flag[(gid * GBLK + lid) << 4], (unsigned)(t + 1),
                                   __ATOMIC_RELAXED, __HIP_MEMORY_SCOPE_AGENT);
            // fp32 outputs off the critical path, after the flag
            const size_t o = ((size_t)(bb0 + b) * SS + t) * HH + hc0 + jp;
            *(float2*)&p.out_h[o] = make_float2(hn2[0], hn2[1]);
            *(float2*)&p.out_c[o] = make_float2(cn2[0], cn2[1]);
        }
        if (t == SS - 1) break;
        // ---- hide barrier propagation: x-part of t+1 (h-independent) ----
        acc = (f32x4){0.f, 0.f, 0.f, 0.f};
        acc = xpart(t + 1, acc);
    }

    // ---- end-of-run: last block resets flags for the next graph replay ----
    __syncthreads();
    if (tid == 0) {
        unsigned v = __hip_atomic_fetch_add(&g_done, 1u, __ATOMIC_RELAXED,
                                            __HIP_MEMORY_SCOPE_AGENT) + 1;
        if (v == NBLK) {
            for (int i = 0; i < NBLK; ++i)
                __hip_atomic_store(&g_flag[i << 4], 0u, __ATOMIC_RELAXED,
                                   __HIP_MEMORY_SCOPE_AGENT);
            __hip_atomic_store(&g_done, 0u, __ATOMIC_RELAXED,
                               __HIP_MEMORY_SCOPE_AGENT);
        }
    }
}

extern "C" void kernel_launch(void* const* d_in, const int* in_sizes, int n_in,
                              void* d_out, int out_size, void* d_ws, size_t ws_size,
                              hipStream_t stream) {
    (void)in_sizes; (void)n_in; (void)d_ws; (void)ws_size; (void)out_size;
    Params p;
    p.x = (const float*)d_in[0];
    for (int g = 0; g < 4; ++g) {
        p.Wi[g]   = (const float*)d_in[1 + g];
        p.Wh[g]   = (const float*)d_in[5 + g];
        p.bias[g] = (const float*)d_in[9 + g];
    }
    p.out_h = (float*)d_out;
    p.out_c = p.out_h + (size_t)BB * SS * HH;
    lstm_mfma<<<dim3(NBLK), dim3(256), 0, stream>>>(p);
}